// Round 8
// baseline (211.610 us; speedup 1.0000x reference)
//
#include <hip/hip_runtime.h>
#include <hip/hip_bf16.h>

// Fused MHA fwd: out = softmax(scale*Q@K^T + bias) @ V
// B=2 H=16 S=2048 D=64, fp32 in/out, bf16 MFMA.
// R3 (84.5us, best): XOR-swizzled LDS, 16x16 MFMA, 4x16q waves, P via LDS.
// R4/R9 (staging depth/granularity): neutral. R5-R7, R10 (P-path/VALU cuts):
//   regressed. Accounting: ~50% of SIMD issue slots have ALL 4 resident waves
//   waiting (lgkm/vm/barrier). VALU cuts can't touch that; only more
//   independent waves can. Wave count is grid-capped: 4096 waves = 16/CU.
// R11: kv-split x2. R3 body VERBATIM; grid 2048, each block does 16 of the
//   32 kv-tiles. Max-free softmax is associative: halves write raw O + l
//   (half0 -> Out + L0, half1 -> ws Opart + L1); combine kernel does
//   (O0+O1)/(l0+l1). LDS 24KB -> 6 blocks/CU -> 24 waves/CU (+50%).
//   Launcher falls back to exact-R3 single-pass if ws_size < 34MB.

#define SEQ 2048
#define DH  64
#define BHN 32
#define NTILE (SEQ / 64)
#define LOG2E 1.44269504088896f

typedef __attribute__((ext_vector_type(8))) short bf16x8;
typedef __attribute__((ext_vector_type(4))) float f32x4;
typedef __attribute__((ext_vector_type(8))) short short8v;

__device__ inline short f2b(float x) {
    union { float f; unsigned u; } v; v.f = x;
    unsigned r = v.u + 0x7fff + ((v.u >> 16) & 1);
    return (short)(r >> 16);
}

__device__ inline void gl_lds16(const void* g, void* l) {
    __builtin_amdgcn_global_load_lds(
        (const __attribute__((address_space(1))) void*)g,
        (__attribute__((address_space(3))) void*)l, 16, 0, 0);
}

// ---- fused prep: K fp32->bf16 (same layout) + V fp32->bf16 transposed ----
__global__ __launch_bounds__(256)
void prep_kv(const float* __restrict__ K, const float* __restrict__ V,
             short* __restrict__ Kb, short* __restrict__ Vt) {
    __shared__ short t[64 * 72];
    const int tid = threadIdx.x;
    const int bh = blockIdx.x >> 5, st = blockIdx.x & 31, s0 = st * 64;

    {
        const float* Kp = K + ((size_t)bh * SEQ + s0) * DH;
        short* Ko = Kb + ((size_t)bh * SEQ + s0) * DH;
        #pragma unroll
        for (int i = 0; i < 2; ++i) {
            size_t o = (size_t)(tid + i * 256) * 8;
            f32x4 a = *(const f32x4*)(Kp + o);
            f32x4 b = *(const f32x4*)(Kp + o + 4);
            short8v s;
            #pragma unroll
            for (int j = 0; j < 4; ++j) { s[j] = f2b(a[j]); s[4 + j] = f2b(b[j]); }
            *(short8v*)(Ko + o) = s;
        }
    }

    const float* Vb = V + (size_t)bh * SEQ * DH + (size_t)s0 * DH;
    #pragma unroll
    for (int i = 0; i < 4; ++i) {
        int c = tid + i * 256, s = c >> 4, c4 = c & 15;
        f32x4 v = *(const f32x4*)(Vb + s * DH + c4 * 4);
        #pragma unroll
        for (int j = 0; j < 4; ++j) t[s * 72 + c4 * 4 + j] = f2b(v[j]);
    }
    __syncthreads();
    const int d = tid >> 2, part = tid & 3;
    short8v lo, hi;
    #pragma unroll
    for (int j = 0; j < 8; ++j) {
        lo[j] = t[(part * 16 + j) * 72 + d];
        hi[j] = t[(part * 16 + 8 + j) * 72 + d];
    }
    short* outp = Vt + (size_t)bh * DH * SEQ + (size_t)d * SEQ + s0 + part * 16;
    *(short8v*)outp = lo;
    *(short8v*)(outp + 8) = hi;
}

// ---- main fused attention (R3 body; template selects kv-split) ----
// LDS layouts XOR-swizzled: logical (row, chunk c of 8 shorts) lives at
// physical chunk (c ^ (row&7)); staging fetches global chunk c^(row&7) into
// physical chunk c; reads use (c ^ (row&7)). Proven zero-conflict (R3).
template<int SPLIT>
__global__ __launch_bounds__(256, 6)
void mha_main(const float* __restrict__ Q, const float* __restrict__ Bias,
              const short* __restrict__ Kb, const short* __restrict__ Vt,
              float* __restrict__ Out, float* __restrict__ Opart,
              float* __restrict__ Lp0, float* __restrict__ Lp1)
{
    __shared__ short lds_k[64 * DH];      // K tile [n][d], swizzled
    __shared__ short lds_v[DH * 64];      // Vt tile [d][n], swizzled
    __shared__ short lds_p[4 * 16 * 64];  // per-wave P [m][n], swizzled

    const int tid = threadIdx.x, lane = tid & 63, wave = tid >> 6;
    const int l15 = lane & 15, l4 = lane >> 4;
    const int bid = blockIdx.x;
    const int half = SPLIT ? (bid >> 10) : 0;
    const int rest = SPLIT ? (bid & 1023) : bid;
    const int qb = rest & 31, bh = rest >> 5;
    const int q0 = qb * 64;
    const int qw = q0 + wave * 16;

    const float* Qb = Q + (size_t)bh * SEQ * DH;
    const short* Kh = Kb + (size_t)bh * SEQ * DH;
    const short* Vh = Vt + (size_t)bh * DH * SEQ;

    // Q fragments (A-layout: m=l15, k=ks*32+l4*8+j), pre-scaled by 1/8
    bf16x8 qf[2];
    {
        const float* qp = Qb + (size_t)(qw + l15) * DH;
        #pragma unroll
        for (int ks = 0; ks < 2; ++ks) {
            short tmp[8];
            #pragma unroll
            for (int j = 0; j < 8; ++j) tmp[j] = f2b(qp[ks * 32 + l4 * 8 + j] * 0.125f);
            qf[ks] = *reinterpret_cast<bf16x8*>(tmp);
        }
    }

    f32x4 o_acc[4];
    #pragma unroll
    for (int dt = 0; dt < 4; ++dt) o_acc[dt] = f32x4{0.f, 0.f, 0.f, 0.f};
    float l_part[4] = {0.f, 0.f, 0.f, 0.f};

    // staging: lane's LDS slot fixed (base + lane*16B); fetch the swizzled
    // global chunk so LDS physical chunk c holds global chunk c^(row&7).
    const short* kg[2]; const short* vg[2]; short* kl[2]; short* vl[2];
    #pragma unroll
    for (int p = 0; p < 2; ++p) {
        int slot = p * 256 + wave * 64 + lane;   // 0..511
        int r_ = slot >> 3;                      // row 0..63
        int c_ = slot & 7;                       // physical 16B chunk
        int cg = c_ ^ (r_ & 7);                  // global chunk to fetch
        kg[p] = Kh + (size_t)r_ * DH + cg * 8;
        vg[p] = Vh + (size_t)r_ * SEQ + cg * 8;
        kl[p] = &lds_k[(size_t)(p * 256 + wave * 64) * 8];
        vl[p] = &lds_v[(size_t)(p * 256 + wave * 64) * 8];
    }
    const float* bp0 = Bias + (size_t)(qw + l4 * 4) * SEQ + l15;
    short* pw = &lds_p[wave * 16 * 64];
    const int swz = l15 & 7;                     // read-side XOR

    const int kt0 = SPLIT ? half * (NTILE / 2) : 0;
    const int kt1 = SPLIT ? kt0 + (NTILE / 2) : NTILE;

    for (int kt = kt0; kt < kt1; ++kt) {
        const int k0 = kt * 64;
        __syncthreads();                          // prior tile reads done
        gl_lds16(kg[0] + (size_t)k0 * DH, kl[0]);
        gl_lds16(kg[1] + (size_t)k0 * DH, kl[1]);
        gl_lds16(vg[0] + k0, vl[0]);
        gl_lds16(vg[1] + k0, vl[1]);

        // bias -> MFMA C init (C-layout: row=l4*4+r, col=nt*16+l15)
        f32x4 sacc[4];
        const float* bp = bp0 + k0;
        #pragma unroll
        for (int nt = 0; nt < 4; ++nt)
            #pragma unroll
            for (int r = 0; r < 4; ++r)
                sacc[nt][r] = bp[(size_t)r * SEQ + nt * 16];

        __syncthreads();                          // staging complete

        #pragma unroll
        for (int ks = 0; ks < 2; ++ks)
            #pragma unroll
            for (int nt = 0; nt < 4; ++nt) {
                int cc = (ks * 4 + l4) ^ swz;
                bf16x8 kf = *(const bf16x8*)&lds_k[(nt * 16 + l15) * DH + cc * 8];
                sacc[nt] = __builtin_amdgcn_mfma_f32_16x16x32_bf16(qf[ks], kf, sacc[nt], 0, 0, 0);
            }

        // max-free softmax; P -> per-wave LDS (swizzled), per-lane l partials
        #pragma unroll
        for (int r = 0; r < 4; ++r) {
            const int prow = l4 * 4 + r;
            const int rsw = prow & 7;
            #pragma unroll
            for (int nt = 0; nt < 4; ++nt) {
                float pv = __builtin_amdgcn_exp2f(sacc[nt][r] * LOG2E);
                l_part[r] += pv;
                int pc = (nt * 2 + (l15 >> 3)) ^ rsw;     // swizzled 8-short chunk
                pw[prow * 64 + pc * 8 + (l15 & 7)] = f2b(pv);
            }
        }

        // O += P @ V
        #pragma unroll
        for (int ks = 0; ks < 2; ++ks) {
            int cc = (ks * 4 + l4) ^ swz;
            bf16x8 pf = *(const bf16x8*)&pw[l15 * 64 + cc * 8];
            #pragma unroll
            for (int dt = 0; dt < 4; ++dt) {
                bf16x8 vf = *(const bf16x8*)&lds_v[(dt * 16 + l15) * DH + cc * 8];
                o_acc[dt] = __builtin_amdgcn_mfma_f32_16x16x32_bf16(pf, vf, o_acc[dt], 0, 0, 0);
            }
        }
    }

    // l reduction across the 16-lane row groups
    #pragma unroll
    for (int r = 0; r < 4; ++r) {
        float s = l_part[r];
        #pragma unroll
        for (int m = 1; m < 16; m <<= 1) s += __shfl_xor(s, m, 64);
        l_part[r] = s;
    }

    if (!SPLIT) {
        float* Ob = Out + (size_t)bh * SEQ * DH;
        #pragma unroll
        for (int r = 0; r < 4; ++r) {
            float inv = 1.0f / l_part[r];
            float* op = Ob + (size_t)(qw + l4 * 4 + r) * DH + l15;
            #pragma unroll
            for (int dt = 0; dt < 4; ++dt) op[dt * 16] = o_acc[dt][r] * inv;
        }
    } else {
        // raw (unnormalized) partials; combine kernel divides by l0+l1
        float* ob = (half ? Opart : Out) + (size_t)bh * SEQ * DH;
        #pragma unroll
        for (int r = 0; r < 4; ++r) {
            float* op = ob + (size_t)(qw + l4 * 4 + r) * DH + l15;
            #pragma unroll
            for (int dt = 0; dt < 4; ++dt) op[dt * 16] = o_acc[dt][r];
        }
        float* Lh = (half ? Lp1 : Lp0) + (size_t)bh * SEQ;
        if (l15 == 0) {
            #pragma unroll
            for (int r = 0; r < 4; ++r) Lh[qw + l4 * 4 + r] = l_part[r];
        }
    }
}

// ---- combine: Out = (Out + Opart) / (l0 + l1) ----
__global__ __launch_bounds__(256)
void combine(float* __restrict__ Out, const float* __restrict__ Opart,
             const float* __restrict__ L0v, const float* __restrict__ L1v)
{
    const int gid = blockIdx.x * 256 + threadIdx.x;   // 524288 threads
    const int row = gid >> 3;                         // q-row 0..65535
    const int d0 = (gid & 7) * 8;
    const float li = 1.0f / (L0v[row] + L1v[row]);
    float* op = Out + (size_t)row * DH + d0;
    const float* pp = Opart + (size_t)row * DH + d0;
    f32x4 a0 = *(const f32x4*)op,       a1 = *(const f32x4*)pp;
    f32x4 b0 = *(const f32x4*)(op + 4), b1 = *(const f32x4*)(pp + 4);
    #pragma unroll
    for (int j = 0; j < 4; ++j) {
        a0[j] = (a0[j] + a1[j]) * li;
        b0[j] = (b0[j] + b1[j]) * li;
    }
    *(f32x4*)op = a0;
    *(f32x4*)(op + 4) = b0;
}

extern "C" void kernel_launch(void* const* d_in, const int* in_sizes, int n_in,
                              void* d_out, int out_size, void* d_ws, size_t ws_size,
                              hipStream_t stream) {
    const float* Q    = (const float*)d_in[0];
    const float* K    = (const float*)d_in[1];
    const float* V    = (const float*)d_in[2];
    const float* Bias = (const float*)d_in[3];
    float* O          = (float*)d_out;

    short* Kb = (short*)d_ws;                        // 8 MB
    short* Vt = Kb + (size_t)BHN * SEQ * DH;         // 8 MB
    float* Opart = (float*)(Vt + (size_t)BHN * SEQ * DH);   // 16.8 MB
    float* L0v = Opart + (size_t)BHN * SEQ * DH;     // 256 KB
    float* L1v = L0v + (size_t)BHN * SEQ;            // 256 KB

    const size_t need_split =
        (size_t)2 * BHN * SEQ * DH * sizeof(short) +
        ((size_t)BHN * SEQ * DH + 2 * (size_t)BHN * SEQ) * sizeof(float);

    prep_kv<<<dim3(BHN * 32), dim3(256), 0, stream>>>(K, V, Kb, Vt);

    if (ws_size >= need_split) {
        mha_main<1><<<dim3(2 * BHN * 32), dim3(256), 0, stream>>>(
            Q, Bias, Kb, Vt, O, Opart, L0v, L1v);
        combine<<<dim3(BHN * SEQ * DH / (256 * 8)), dim3(256), 0, stream>>>(
            O, Opart, L0v, L1v);
    } else {
        mha_main<0><<<dim3(BHN * 32), dim3(256), 0, stream>>>(
            Q, Bias, Kb, Vt, O, Opart, L0v, L1v);
    }
}